// Round 11
// baseline (123.040 us; speedup 1.0000x reference)
//
#include <hip/hip_runtime.h>
#include <hip/hip_bf16.h>

#define N_NODES 100000
#define N_EDGES 640000
#define D 128
#define BN_EPS 1e-5f
#define NB_FILL 2500 // E/256
#define NB_CVT 6250  // N*D/8/256
#define NREP 64      // stats replication factor
#define BM 64        // k_mm rows per block
#define CS_LD 130    // Cs leading dim (float)
#define SLOTS 48     // bucket slots per node (max degree; P(exceed) ~ e^-55)

typedef __attribute__((ext_vector_type(8))) short short8;
typedef __attribute__((ext_vector_type(4))) float f32x4;

__device__ inline unsigned int f2bf(float f) {  // RNE float->bf16 (low 16)
    unsigned int u = __builtin_bit_cast(unsigned int, f);
    return (u + 0x7FFFu + ((u >> 16) & 1u)) >> 16;
}
__device__ inline float bflo(unsigned int p) { return __builtin_bit_cast(float, p << 16); }
__device__ inline float bfhi(unsigned int p) { return __builtin_bit_cast(float, p & 0xFFFF0000u); }

// ---------------- zero cnt + rep (must precede k_prep's fill) ----------------
__global__ void k_zero(int* __restrict__ cnt, float* __restrict__ rep) {
    int i = blockIdx.x * 256 + threadIdx.x;
    if (i < N_NODES) cnt[i] = 0;
    if (i < NREP * 256) rep[i] = 0.0f;
}

// ---------------- fused prep: fill buckets || cvt x->bf16 || cvt W->fragment-major ----------------
__global__ __launch_bounds__(256) void k_prep(const int* __restrict__ ei, int* __restrict__ cnt,
                                              int* __restrict__ buck,
                                              const float* __restrict__ x, uint4* __restrict__ xb,
                                              const float* __restrict__ W,
                                              unsigned short* __restrict__ Wfrag) {
    const int bid = blockIdx.x;
    const int t = threadIdx.x;
    if (bid < NB_FILL) {
        // fill blocks first: latency/atomic-bound, overlaps with streaming cvt below
        const int e = bid * 256 + t;
        if (e < N_EDGES) {
            const int src = ei[e];
            const int d = ei[N_EDGES + e];
            const int slot = atomicAdd(&cnt[d], 1);
            if (slot < SLOTS) buck[(size_t)d * SLOTS + slot] = src;
        }
    } else if (bid < NB_FILL + NB_CVT) {
        const size_t i = (size_t)(bid - NB_FILL) * 256 + t;  // one uint4 = 8 bf16
        const float4* xg = (const float4*)x;
        float4 a = xg[2 * i], c = xg[2 * i + 1];
        uint4 o;
        o.x = f2bf(a.x) | (f2bf(a.y) << 16);
        o.y = f2bf(a.z) | (f2bf(a.w) << 16);
        o.z = f2bf(c.x) | (f2bf(c.y) << 16);
        o.w = f2bf(c.z) | (f2bf(c.w) << 16);
        xb[i] = o;
    } else {
        const int i = (bid - NB_FILL - NB_CVT) * 256 + t;  // 0..16383
        const int e  = i & 7;
        const int l  = (i >> 3) & 63;
        const int ct = (i >> 9) & 7;
        const int kk = i >> 12;
        const int lr = l & 15, lk = l >> 4;
        const int k   = kk * 32 + lk * 8 + e;
        const int col = ct * 16 + lr;
        Wfrag[i] = (unsigned short)f2bf(W[(size_t)k * D + col]);
    }
}

// ---------------- gather: one wave per node; unclamped readlane batches ----------------
// lanes >= deg hold (s=0, f=0): row-0 load contributes 0 -- no masking needed.
__global__ __launch_bounds__(256) void k_gather(const int* __restrict__ buck,
                                                const int* __restrict__ cnt,
                                                const unsigned int* __restrict__ xb,
                                                unsigned int* __restrict__ agg) {
    const int t = threadIdx.x;
    const int lane = t & 63;
    const int n = blockIdx.x * 4 + (t >> 6);
    if (n >= N_NODES) return;

    const int deg = cnt[n];
    const float di = rsqrtf((float)(deg + 1));
    const unsigned int hv = xb[(size_t)n * 64 + lane];
    const float dd = di * di;
    float ax = bflo(hv) * dd;
    float ay = bfhi(hv) * dd;

    const int m = (deg > SLOTS) ? SLOTS : deg;  // <= 48 < 64 lanes
    int s_l = 0; float f_l = 0.0f;
    if (lane < m) {
        s_l = buck[(size_t)n * SLOTS + lane];
        f_l = rsqrtf((float)(cnt[s_l] + 1)) * di;
    }

    for (int k = 0; k < m; k += 8) {
        unsigned int v[8];
        float f[8];
#pragma unroll
        for (int i = 0; i < 8; ++i) {
            const int sj = __builtin_amdgcn_readlane(s_l, k + i);
            f[i] = __builtin_bit_cast(float,
                __builtin_amdgcn_readlane(__builtin_bit_cast(int, f_l), k + i));
            v[i] = xb[(size_t)sj * 64 + lane];
        }
#pragma unroll
        for (int i = 0; i < 8; ++i) {
            ax = fmaf(bflo(v[i]), f[i], ax);
            ay = fmaf(bfhi(v[i]), f[i], ay);
        }
    }
    agg[(size_t)n * 64 + lane] = f2bf(ax) | (f2bf(ay) << 16);
}

// ---------------- MFMA GEMM: prepacked B, LDS-staged A, bf16 out via Cs transpose ----------------
__global__ __launch_bounds__(256) void k_mm(const unsigned int* __restrict__ agg,
                                            const unsigned short* __restrict__ Wfrag,
                                            const float* __restrict__ b,
                                            unsigned int* __restrict__ outb,
                                            float* __restrict__ rep) {
    __shared__ __align__(16) char U[BM * CS_LD * 4];
    uint4 (*As)[16] = (uint4(*)[16])U;
    float* Cs = (float*)U;
    __shared__ float lsum[4][128];
    __shared__ float lsq[4][128];

    const int t = threadIdx.x;
    const int w = t >> 6;
    const int l = t & 63;
    const int lr = l & 15;
    const int lk = l >> 4;
    const int r0 = blockIdx.x * BM;

    const uint4* aggv = (const uint4*)agg;
#pragma unroll
    for (int it = 0; it < 4; ++it) {
        const int idx = it * 256 + t;
        const int row = idx >> 4;
        const int c   = idx & 15;
        int grow = r0 + row; if (grow >= N_NODES) grow = N_NODES - 1;
        As[row][c ^ (row & 15)] = aggv[(size_t)grow * 16 + c];
    }
    __syncthreads();

    const int arow = w * 16 + lr;
    short8 a[4];
#pragma unroll
    for (int kk = 0; kk < 4; ++kk)
        a[kk] = *(const short8*)&As[arow][(kk * 4 + lk) ^ (arow & 15)];
    __syncthreads();  // all As reads done; U may be reused as Cs

    f32x4 acc[8];
#pragma unroll
    for (int ct = 0; ct < 8; ++ct) acc[ct] = (f32x4)(0.0f);

#pragma unroll
    for (int kk = 0; kk < 4; ++kk) {
#pragma unroll
        for (int ct = 0; ct < 8; ++ct) {
            const short8 bb = *(const short8*)(Wfrag + ((((kk * 8 + ct) << 6) + l) << 3));
            acc[ct] = __builtin_amdgcn_mfma_f32_16x16x32_bf16(a[kk], bb, acc[ct], 0, 0, 0);
        }
    }

    float s[8], s2[8];
#pragma unroll
    for (int ct = 0; ct < 8; ++ct) { s[ct] = 0.0f; s2[ct] = 0.0f; }

#pragma unroll
    for (int ct = 0; ct < 8; ++ct) {
        const float bias = b[ct * 16 + lr];
#pragma unroll
        for (int r = 0; r < 4; ++r) {
            const int lrow = w * 16 + lk * 4 + r;
            const float v = fmaxf(acc[ct][r] + bias, 0.0f);
            if (r0 + lrow < N_NODES) {
                s[ct] += v;
                s2[ct] = fmaf(v, v, s2[ct]);
            }
            Cs[lrow * CS_LD + ct * 16 + lr] = v;
        }
    }
#pragma unroll
    for (int ct = 0; ct < 8; ++ct) {
        s[ct]  += __shfl_xor(s[ct], 16);  s[ct]  += __shfl_xor(s[ct], 32);
        s2[ct] += __shfl_xor(s2[ct], 16); s2[ct] += __shfl_xor(s2[ct], 32);
    }
    if (l < 16) {
#pragma unroll
        for (int ct = 0; ct < 8; ++ct) {
            lsum[w][ct * 16 + lr] = s[ct];
            lsq[w][ct * 16 + lr]  = s2[ct];
        }
    }
    __syncthreads();

#pragma unroll
    for (int i = 0; i < 4; ++i) {
        const int v = i * 256 + t;          // 0..1023 uint4 slots (8 bf16 each)
        const int row = v >> 4;
        const int q   = v & 15;
        if (r0 + row < N_NODES) {
            const float* p = &Cs[row * CS_LD + q * 8];
            uint4 o;
            o.x = f2bf(p[0]) | (f2bf(p[1]) << 16);
            o.y = f2bf(p[2]) | (f2bf(p[3]) << 16);
            o.z = f2bf(p[4]) | (f2bf(p[5]) << 16);
            o.w = f2bf(p[6]) | (f2bf(p[7]) << 16);
            ((uint4*)outb)[(size_t)(r0 + row) * 16 + q] = o;
        }
    }

    if (t < 128) {
        float* r = rep + (blockIdx.x & (NREP - 1)) * 256;
        atomicAdd(&r[t],       lsum[0][t] + lsum[1][t] + lsum[2][t] + lsum[3][t]);
        atomicAdd(&r[128 + t], lsq[0][t] + lsq[1][t] + lsq[2][t] + lsq[3][t]);
    }
}

// ---------------- collapse replicated stats -> folded scale/shift ----------------
__global__ __launch_bounds__(256) void k_red(const float* __restrict__ rep,
                                             const float* __restrict__ gamma,
                                             const float* __restrict__ beta,
                                             float* __restrict__ sclsft) {
    __shared__ float sh[256];
    const int t = threadIdx.x;
    float s = 0.0f;
    for (int r = 0; r < NREP; ++r) s += rep[r * 256 + t];
    sh[t] = s;
    __syncthreads();
    if (t < 128) {
        const float inv_n = 1.0f / (float)N_NODES;
        const float mean = sh[t] * inv_n;
        const float var = sh[128 + t] * inv_n - mean * mean;
        const float sc = gamma[t] * rsqrtf(var + BN_EPS);
        sclsft[t]       = sc;
        sclsft[128 + t] = beta[t] - mean * sc;
    }
}

// ---------------- normalize: read bf16 outb, write fp32 out ----------------
__global__ __launch_bounds__(256) void k_norm(const uint4* __restrict__ outb,
                                              float4* __restrict__ out,
                                              const float* __restrict__ sclsft) {
    __shared__ float sc[256];
    const int t = threadIdx.x;
    sc[t] = sclsft[t];
    __syncthreads();
    const int i = blockIdx.x * 256 + t;      // uint4 slot; N*16 total
    if (i >= N_NODES * 16) return;
    const int c0 = (i & 15) * 8;
    const uint4 v = outb[i];
    float4 o0, o1;
    o0.x = fmaf(bflo(v.x), sc[c0 + 0], sc[128 + c0 + 0]);
    o0.y = fmaf(bfhi(v.x), sc[c0 + 1], sc[128 + c0 + 1]);
    o0.z = fmaf(bflo(v.y), sc[c0 + 2], sc[128 + c0 + 2]);
    o0.w = fmaf(bfhi(v.y), sc[c0 + 3], sc[128 + c0 + 3]);
    o1.x = fmaf(bflo(v.z), sc[c0 + 4], sc[128 + c0 + 4]);
    o1.y = fmaf(bfhi(v.z), sc[c0 + 5], sc[128 + c0 + 5]);
    o1.z = fmaf(bflo(v.w), sc[c0 + 6], sc[128 + c0 + 6]);
    o1.w = fmaf(bfhi(v.w), sc[c0 + 7], sc[128 + c0 + 7]);
    out[(size_t)i * 2]     = o0;
    out[(size_t)i * 2 + 1] = o1;
}

extern "C" void kernel_launch(void* const* d_in, const int* in_sizes, int n_in,
                              void* d_out, int out_size, void* d_ws, size_t ws_size,
                              hipStream_t stream) {
    const float* x     = (const float*)d_in[0];
    const int*   ei    = (const int*)d_in[1];
    const float* W     = (const float*)d_in[2];
    const float* b     = (const float*)d_in[3];
    const float* gamma = (const float*)d_in[4];
    const float* beta  = (const float*)d_in[5];
    float* out = (float*)d_out;

    char* ws = (char*)d_ws;
    int*            cnt    = (int*)(ws + 0);                         // 400 KB
    float*          rep    = (float*)(ws + (512u << 10));            // 64 KB
    float*          sclsft = (float*)(ws + (640u << 10));            // 1 KB
    unsigned short* Wfrag  = (unsigned short*)(ws + (704u << 10));   // 32 KB
    int*            buck   = (int*)(ws + (1024u << 10));             // 18.3 MB (N*48*4)
    unsigned int*   xb     = (unsigned int*)(ws + (24576u << 10));   // 25.6 MB (reused as outb)
    unsigned int*   agg    = (unsigned int*)(ws + (57344u << 10));   // 25.6 MB

    unsigned int* outb = xb;  // xb dead after k_gather; k_mm writes here

    k_zero<<<(N_NODES + 255) / 256, 256, 0, stream>>>(cnt, rep);
    k_prep<<<NB_FILL + NB_CVT + 64, 256, 0, stream>>>(ei, cnt, buck, x, (uint4*)xb, W, Wfrag);
    k_gather<<<(N_NODES + 3) / 4, 256, 0, stream>>>(buck, cnt, xb, agg);
    k_mm<<<(N_NODES + BM - 1) / BM, 256, 0, stream>>>(agg, Wfrag, b, outb, rep);
    k_red<<<1, 256, 0, stream>>>(rep, gamma, beta, sclsft);
    k_norm<<<(N_NODES * 16 + 255) / 256, 256, 0, stream>>>((const uint4*)outb, (float4*)out,
                                                           sclsft);
}

// Round 12
// 118.243 us; speedup vs baseline: 1.0406x; 1.0406x over previous
//
#include <hip/hip_runtime.h>
#include <hip/hip_bf16.h>

#define N_NODES 100000
#define N_EDGES 640000
#define D 128
#define BN_EPS 1e-5f
#define NB_FILL 2500 // E/256
#define NB_CVT 6250  // N*D/8/256
#define NREP 64      // stats replication factor
#define BM 64        // k_mm rows per block
#define CS_LD 130    // Cs leading dim (float)
#define SLOTS 16     // inline bucket slots (1 cache line per node)
#define OSLOTS 32    // overflow slots (deg 17..48); P(deg>48) ~ e^-55

typedef __attribute__((ext_vector_type(8))) short short8;
typedef __attribute__((ext_vector_type(4))) float f32x4;

__device__ inline unsigned int f2bf(float f) {  // RNE float->bf16 (low 16)
    unsigned int u = __builtin_bit_cast(unsigned int, f);
    return (u + 0x7FFFu + ((u >> 16) & 1u)) >> 16;
}
__device__ inline float bflo(unsigned int p) { return __builtin_bit_cast(float, p << 16); }
__device__ inline float bfhi(unsigned int p) { return __builtin_bit_cast(float, p & 0xFFFF0000u); }

// ---------------- zero cnt + rep (must precede k_prep's fill) ----------------
__global__ void k_zero(int* __restrict__ cnt, float* __restrict__ rep) {
    int i = blockIdx.x * 256 + threadIdx.x;
    if (i < N_NODES) cnt[i] = 0;
    if (i < NREP * 256) rep[i] = 0.0f;
}

// ---------------- fused prep, ROLE-INTERLEAVED: fill ∥ cvt x ∥ cvt W ----------------
__global__ __launch_bounds__(256) void k_prep(const int* __restrict__ ei, int* __restrict__ cnt,
                                              int* __restrict__ buck, int* __restrict__ buck2,
                                              const float* __restrict__ x, uint4* __restrict__ xb,
                                              const float* __restrict__ W,
                                              unsigned short* __restrict__ Wfrag) {
    const int bid = blockIdx.x;
    const int t = threadIdx.x;
    int xi = -1;
    if (bid < 2 * NB_FILL) {
        if (bid & 1) {
            // fill role, interleaved 1:1 with cvt so atomic stalls hide under streaming
            const int e = (bid >> 1) * 256 + t;
            if (e < N_EDGES) {
                const int src = ei[e];
                const int d = ei[N_EDGES + e];
                const int slot = atomicAdd(&cnt[d], 1);
                if (slot < SLOTS) buck[(size_t)d * SLOTS + slot] = src;
                else if (slot < SLOTS + OSLOTS) buck2[(size_t)d * OSLOTS + slot - SLOTS] = src;
            }
            return;
        }
        xi = bid >> 1;
    } else if (bid < NB_FILL + NB_CVT) {
        xi = bid - NB_FILL;  // 2500..6249
    } else {
        const int i = (bid - NB_FILL - NB_CVT) * 256 + t;  // 0..16383
        const int e  = i & 7;
        const int l  = (i >> 3) & 63;
        const int ct = (i >> 9) & 7;
        const int kk = i >> 12;
        const int lr = l & 15, lk = l >> 4;
        const int k   = kk * 32 + lk * 8 + e;
        const int col = ct * 16 + lr;
        Wfrag[i] = (unsigned short)f2bf(W[(size_t)k * D + col]);
        return;
    }
    const size_t i = (size_t)xi * 256 + t;  // one uint4 = 8 bf16
    const float4* xg = (const float4*)x;
    float4 a = xg[2 * i], c = xg[2 * i + 1];
    uint4 o;
    o.x = f2bf(a.x) | (f2bf(a.y) << 16);
    o.y = f2bf(a.z) | (f2bf(a.w) << 16);
    o.z = f2bf(c.x) | (f2bf(c.y) << 16);
    o.w = f2bf(c.z) | (f2bf(c.w) << 16);
    xb[i] = o;
}

// ---------------- gather: one wave per node; unclamped readlane batches ----------------
// lanes >= deg hold (s=0, f=0): row-0 load contributes 0 -- no masking needed.
__global__ __launch_bounds__(256) void k_gather(const int* __restrict__ buck,
                                                const int* __restrict__ buck2,
                                                const int* __restrict__ cnt,
                                                const unsigned int* __restrict__ xb,
                                                unsigned int* __restrict__ agg) {
    const int t = threadIdx.x;
    const int lane = t & 63;
    const int n = blockIdx.x * 4 + (t >> 6);
    if (n >= N_NODES) return;

    const int deg = cnt[n];
    const float di = rsqrtf((float)(deg + 1));
    const unsigned int hv = xb[(size_t)n * 64 + lane];
    const float dd = di * di;
    float ax = bflo(hv) * dd;
    float ay = bfhi(hv) * dd;

    const int m = (deg > SLOTS + OSLOTS) ? (SLOTS + OSLOTS) : deg;  // <= 48 < 64 lanes
    int s_l = 0; float f_l = 0.0f;
    if (lane < m) {
        s_l = (lane < SLOTS) ? buck[(size_t)n * SLOTS + lane]
                             : buck2[(size_t)n * OSLOTS + lane - SLOTS];
        f_l = rsqrtf((float)(cnt[s_l] + 1)) * di;
    }

    for (int k = 0; k < m; k += 8) {
        unsigned int v[8];
        float f[8];
#pragma unroll
        for (int i = 0; i < 8; ++i) {
            const int sj = __builtin_amdgcn_readlane(s_l, k + i);
            f[i] = __builtin_bit_cast(float,
                __builtin_amdgcn_readlane(__builtin_bit_cast(int, f_l), k + i));
            v[i] = xb[(size_t)sj * 64 + lane];
        }
#pragma unroll
        for (int i = 0; i < 8; ++i) {
            ax = fmaf(bflo(v[i]), f[i], ax);
            ay = fmaf(bfhi(v[i]), f[i], ay);
        }
    }
    agg[(size_t)n * 64 + lane] = f2bf(ax) | (f2bf(ay) << 16);
}

// ---------------- MFMA GEMM: prepacked B, LDS-staged A, bf16 out via Cs transpose ----------------
__global__ __launch_bounds__(256) void k_mm(const unsigned int* __restrict__ agg,
                                            const unsigned short* __restrict__ Wfrag,
                                            const float* __restrict__ b,
                                            unsigned int* __restrict__ outb,
                                            float* __restrict__ rep) {
    __shared__ __align__(16) char U[BM * CS_LD * 4];
    uint4 (*As)[16] = (uint4(*)[16])U;
    float* Cs = (float*)U;
    __shared__ float lsum[4][128];
    __shared__ float lsq[4][128];

    const int t = threadIdx.x;
    const int w = t >> 6;
    const int l = t & 63;
    const int lr = l & 15;
    const int lk = l >> 4;
    const int r0 = blockIdx.x * BM;

    const uint4* aggv = (const uint4*)agg;
#pragma unroll
    for (int it = 0; it < 4; ++it) {
        const int idx = it * 256 + t;
        const int row = idx >> 4;
        const int c   = idx & 15;
        int grow = r0 + row; if (grow >= N_NODES) grow = N_NODES - 1;
        As[row][c ^ (row & 15)] = aggv[(size_t)grow * 16 + c];
    }
    __syncthreads();

    const int arow = w * 16 + lr;
    short8 a[4];
#pragma unroll
    for (int kk = 0; kk < 4; ++kk)
        a[kk] = *(const short8*)&As[arow][(kk * 4 + lk) ^ (arow & 15)];
    __syncthreads();  // all As reads done; U may be reused as Cs

    f32x4 acc[8];
#pragma unroll
    for (int ct = 0; ct < 8; ++ct) acc[ct] = (f32x4)(0.0f);

#pragma unroll
    for (int kk = 0; kk < 4; ++kk) {
#pragma unroll
        for (int ct = 0; ct < 8; ++ct) {
            const short8 bb = *(const short8*)(Wfrag + ((((kk * 8 + ct) << 6) + l) << 3));
            acc[ct] = __builtin_amdgcn_mfma_f32_16x16x32_bf16(a[kk], bb, acc[ct], 0, 0, 0);
        }
    }

    float s[8], s2[8];
#pragma unroll
    for (int ct = 0; ct < 8; ++ct) { s[ct] = 0.0f; s2[ct] = 0.0f; }

#pragma unroll
    for (int ct = 0; ct < 8; ++ct) {
        const float bias = b[ct * 16 + lr];
#pragma unroll
        for (int r = 0; r < 4; ++r) {
            const int lrow = w * 16 + lk * 4 + r;
            const float v = fmaxf(acc[ct][r] + bias, 0.0f);
            if (r0 + lrow < N_NODES) {
                s[ct] += v;
                s2[ct] = fmaf(v, v, s2[ct]);
            }
            Cs[lrow * CS_LD + ct * 16 + lr] = v;
        }
    }
#pragma unroll
    for (int ct = 0; ct < 8; ++ct) {
        s[ct]  += __shfl_xor(s[ct], 16);  s[ct]  += __shfl_xor(s[ct], 32);
        s2[ct] += __shfl_xor(s2[ct], 16); s2[ct] += __shfl_xor(s2[ct], 32);
    }
    if (l < 16) {
#pragma unroll
        for (int ct = 0; ct < 8; ++ct) {
            lsum[w][ct * 16 + lr] = s[ct];
            lsq[w][ct * 16 + lr]  = s2[ct];
        }
    }
    __syncthreads();

#pragma unroll
    for (int i = 0; i < 4; ++i) {
        const int v = i * 256 + t;          // 0..1023 uint4 slots (8 bf16 each)
        const int row = v >> 4;
        const int q   = v & 15;
        if (r0 + row < N_NODES) {
            const float* p = &Cs[row * CS_LD + q * 8];
            uint4 o;
            o.x = f2bf(p[0]) | (f2bf(p[1]) << 16);
            o.y = f2bf(p[2]) | (f2bf(p[3]) << 16);
            o.z = f2bf(p[4]) | (f2bf(p[5]) << 16);
            o.w = f2bf(p[6]) | (f2bf(p[7]) << 16);
            ((uint4*)outb)[(size_t)(r0 + row) * 16 + q] = o;
        }
    }

    if (t < 128) {
        float* r = rep + (blockIdx.x & (NREP - 1)) * 256;
        atomicAdd(&r[t],       lsum[0][t] + lsum[1][t] + lsum[2][t] + lsum[3][t]);
        atomicAdd(&r[128 + t], lsq[0][t] + lsq[1][t] + lsq[2][t] + lsq[3][t]);
    }
}

// ---------------- collapse replicated stats -> folded scale/shift ----------------
__global__ __launch_bounds__(256) void k_red(const float* __restrict__ rep,
                                             const float* __restrict__ gamma,
                                             const float* __restrict__ beta,
                                             float* __restrict__ sclsft) {
    __shared__ float sh[256];
    const int t = threadIdx.x;
    float s = 0.0f;
    for (int r = 0; r < NREP; ++r) s += rep[r * 256 + t];
    sh[t] = s;
    __syncthreads();
    if (t < 128) {
        const float inv_n = 1.0f / (float)N_NODES;
        const float mean = sh[t] * inv_n;
        const float var = sh[128 + t] * inv_n - mean * mean;
        const float sc = gamma[t] * rsqrtf(var + BN_EPS);
        sclsft[t]       = sc;
        sclsft[128 + t] = beta[t] - mean * sc;
    }
}

// ---------------- normalize: read bf16 outb, write fp32 out ----------------
__global__ __launch_bounds__(256) void k_norm(const uint4* __restrict__ outb,
                                              float4* __restrict__ out,
                                              const float* __restrict__ sclsft) {
    __shared__ float sc[256];
    const int t = threadIdx.x;
    sc[t] = sclsft[t];
    __syncthreads();
    const int i = blockIdx.x * 256 + t;      // uint4 slot; N*16 total
    if (i >= N_NODES * 16) return;
    const int c0 = (i & 15) * 8;
    const uint4 v = outb[i];
    float4 o0, o1;
    o0.x = fmaf(bflo(v.x), sc[c0 + 0], sc[128 + c0 + 0]);
    o0.y = fmaf(bfhi(v.x), sc[c0 + 1], sc[128 + c0 + 1]);
    o0.z = fmaf(bflo(v.y), sc[c0 + 2], sc[128 + c0 + 2]);
    o0.w = fmaf(bfhi(v.y), sc[c0 + 3], sc[128 + c0 + 3]);
    o1.x = fmaf(bflo(v.z), sc[c0 + 4], sc[128 + c0 + 4]);
    o1.y = fmaf(bfhi(v.z), sc[c0 + 5], sc[128 + c0 + 5]);
    o1.z = fmaf(bflo(v.w), sc[c0 + 6], sc[128 + c0 + 6]);
    o1.w = fmaf(bfhi(v.w), sc[c0 + 7], sc[128 + c0 + 7]);
    out[(size_t)i * 2]     = o0;
    out[(size_t)i * 2 + 1] = o1;
}

extern "C" void kernel_launch(void* const* d_in, const int* in_sizes, int n_in,
                              void* d_out, int out_size, void* d_ws, size_t ws_size,
                              hipStream_t stream) {
    const float* x     = (const float*)d_in[0];
    const int*   ei    = (const int*)d_in[1];
    const float* W     = (const float*)d_in[2];
    const float* b     = (const float*)d_in[3];
    const float* gamma = (const float*)d_in[4];
    const float* beta  = (const float*)d_in[5];
    float* out = (float*)d_out;

    char* ws = (char*)d_ws;
    int*            cnt    = (int*)(ws + 0);                         // 400 KB
    float*          rep    = (float*)(ws + (512u << 10));            // 64 KB
    float*          sclsft = (float*)(ws + (640u << 10));            // 1 KB
    unsigned short* Wfrag  = (unsigned short*)(ws + (704u << 10));   // 32 KB
    int*            buck   = (int*)(ws + (1024u << 10));             // 6.4 MB (N*16*4)
    int*            buck2  = (int*)(ws + (8192u << 10));             // 12.8 MB (N*32*4)
    unsigned int*   xb     = (unsigned int*)(ws + (24576u << 10));   // 25.6 MB (reused as outb)
    unsigned int*   agg    = (unsigned int*)(ws + (57344u << 10));   // 25.6 MB

    unsigned int* outb = xb;  // xb dead after k_gather; k_mm writes here

    k_zero<<<(N_NODES + 255) / 256, 256, 0, stream>>>(cnt, rep);
    k_prep<<<NB_FILL + NB_CVT + 64, 256, 0, stream>>>(ei, cnt, buck, buck2, x, (uint4*)xb,
                                                      W, Wfrag);
    k_gather<<<(N_NODES + 3) / 4, 256, 0, stream>>>(buck, buck2, cnt, xb, agg);
    k_mm<<<(N_NODES + BM - 1) / BM, 256, 0, stream>>>(agg, Wfrag, b, outb, rep);
    k_red<<<1, 256, 0, stream>>>(rep, gamma, beta, sclsft);
    k_norm<<<(N_NODES * 16 + 255) / 256, 256, 0, stream>>>((const uint4*)outb, (float4*)out,
                                                           sclsft);
}